// Round 6
// baseline (828.934 us; speedup 1.0000x reference)
//
#include <hip/hip_runtime.h>
#include <math.h>

#define BB 512
#define SS 100
#define HH 768

typedef __bf16 bf16x8 __attribute__((ext_vector_type(8)));
typedef __bf16 bf16x4 __attribute__((ext_vector_type(4)));
typedef float f32x4 __attribute__((ext_vector_type(4)));
typedef float f32x16 __attribute__((ext_vector_type(16)));

__device__ __forceinline__ void gld16(const void* g, void* l) {
    __builtin_amdgcn_global_load_lds((const __attribute__((address_space(1))) char*)g,
                                     (__attribute__((address_space(3))) char*)l, 16, 0, 0);
}

// ---------------- K0: d_rep[b,h] = mean_s X[b,s,h]  (coalesced float4 col-reduce) ----------------
__global__ __launch_bounds__(256) void k_drep(const float* __restrict__ X,
                                              float* __restrict__ drep) {
    int b = blockIdx.x, g = blockIdx.y;
    int lane = threadIdx.x & 63, w = threadIdx.x >> 6;
    const float4* xb = (const float4*)(X + (size_t)b * SS * HH);
    int c4 = g * 64 + lane;
    float4 s = {0.f, 0.f, 0.f, 0.f};
    for (int r = w; r < SS; r += 4) {
        float4 v = xb[r * 192 + c4];
        s.x += v.x; s.y += v.y; s.z += v.z; s.w += v.w;
    }
    __shared__ float4 red[4][64];
    red[w][lane] = s;
    __syncthreads();
    if (w == 0) {
        float4 a0 = red[0][lane], a1 = red[1][lane], a2 = red[2][lane], a3 = red[3][lane];
        float4 o;
        o.x = (a0.x + a1.x + a2.x + a3.x) * (1.0f / SS);
        o.y = (a0.y + a1.y + a2.y + a3.y) * (1.0f / SS);
        o.z = (a0.z + a1.z + a2.z + a3.z) * (1.0f / SS);
        o.w = (a0.w + a1.w + a2.w + a3.w) * (1.0f / SS);
        ((float4*)(drep + (size_t)b * HH))[c4] = o;
    }
}

// ---------------- K1: t = d_rep @ W_rel^T  (fp32 NT, 64x64x16; 0.6 GFLOP) ----------------
__global__ __launch_bounds__(256) void k_gemm_nt(const float* __restrict__ A,
                                                 const float* __restrict__ Bm,
                                                 float* __restrict__ C,
                                                 int N, int K) {
    __shared__ float As[64 * 20];
    __shared__ float Bs[64 * 20];
    int tid = threadIdx.x;
    int ty = tid >> 4, tx = tid & 15;
    int m0 = blockIdx.y * 64, n0 = blockIdx.x * 64;
    int lr = tid >> 2, lc = (tid & 3) * 4;
    float acc[4][4] = {};
    for (int kt = 0; kt < K; kt += 16) {
        *(float4*)(As + lr * 20 + lc) = *(const float4*)(A + (size_t)(m0 + lr) * K + kt + lc);
        *(float4*)(Bs + lr * 20 + lc) = *(const float4*)(Bm + (size_t)(n0 + lr) * K + kt + lc);
        __syncthreads();
        #pragma unroll
        for (int k = 0; k < 16; k += 2) {
            float2 ar[4], br[4];
            #pragma unroll
            for (int ii = 0; ii < 4; ++ii) ar[ii] = *(const float2*)(As + (ty + 16 * ii) * 20 + k);
            #pragma unroll
            for (int jj = 0; jj < 4; ++jj) br[jj] = *(const float2*)(Bs + (tx + 16 * jj) * 20 + k);
            #pragma unroll
            for (int ii = 0; ii < 4; ++ii)
                #pragma unroll
                for (int jj = 0; jj < 4; ++jj)
                    acc[ii][jj] = fmaf(ar[ii].y, br[jj].y, fmaf(ar[ii].x, br[jj].x, acc[ii][jj]));
        }
        __syncthreads();
    }
    #pragma unroll
    for (int ii = 0; ii < 4; ++ii)
        #pragma unroll
        for (int jj = 0; jj < 4; ++jj)
            C[(size_t)(m0 + ty + 16 * ii) * N + n0 + tx + 16 * jj] = acc[ii][jj];
}

// ---------------- K_splitw: W(K x N) -> Wt_h/Wt_l (N x K) bf16 split ----------------
__global__ __launch_bounds__(256) void k_splitw(const float* __restrict__ W,
                                                __bf16* __restrict__ th,
                                                __bf16* __restrict__ tl) {
    __shared__ float tile[32][33];
    int bn = blockIdx.x * 32, bk = blockIdx.y * 32;
    int tx = threadIdx.x & 31, ty = threadIdx.x >> 5;
    for (int r = ty; r < 32; r += 8)
        tile[r][tx] = W[(size_t)(bk + r) * HH + bn + tx];
    __syncthreads();
    for (int r = ty; r < 32; r += 8) {
        float v = tile[tx][r];
        __bf16 hv = (__bf16)v;
        size_t idx = (size_t)(bn + r) * HH + bk + tx;
        th[idx] = hv;
        tl[idx] = (__bf16)(v - (float)hv);
    }
}

// ---------------- K_split+contrel: split X chunk to bf16 hi/lo AND a[b,i]=X[b,i]·u[b]+b00 ----------------
__global__ __launch_bounds__(512) void k_split_contrel(const float* __restrict__ X,
                                                       const float* __restrict__ Wc,
                                                       const float* __restrict__ tmat,
                                                       const float* __restrict__ bmat,
                                                       __bf16* __restrict__ Xh,
                                                       __bf16* __restrict__ Xl,
                                                       float* __restrict__ avec,
                                                       int b_off) {
    __shared__ float4 u4[192];
    int lb = blockIdx.x, half = blockIdx.y;
    int b = b_off + lb;
    int tid = threadIdx.x, lane = tid & 63, w = tid >> 6;
    for (int c = tid; c < 192; c += 512) {
        float4 wc = ((const float4*)Wc)[c];
        float4 tm = ((const float4*)(tmat + (size_t)b * HH))[c];
        float4 o = {wc.x + tm.x, wc.y + tm.y, wc.z + tm.z, wc.w + tm.w};
        u4[c] = o;
    }
    __syncthreads();
    float b00 = bmat[0];
    const float4* xb = (const float4*)(X + (size_t)b * SS * HH);
    bf16x4* xh4 = (bf16x4*)(Xh + (size_t)lb * SS * HH);
    bf16x4* xl4 = (bf16x4*)(Xl + (size_t)lb * SS * HH);
    int rend = half * 50 + 50;
    for (int r = half * 50 + w; r < rend; r += 8) {
        float s = 0.f;
        #pragma unroll
        for (int cc = 0; cc < 3; ++cc) {
            int c = cc * 64 + lane;
            float4 v = xb[r * 192 + c];
            float4 uu = u4[c];
            s = fmaf(v.x, uu.x, fmaf(v.y, uu.y, fmaf(v.z, uu.z, fmaf(v.w, uu.w, s))));
            bf16x4 hv, lv;
            hv[0] = (__bf16)v.x; lv[0] = (__bf16)(v.x - (float)hv[0]);
            hv[1] = (__bf16)v.y; lv[1] = (__bf16)(v.y - (float)hv[1]);
            hv[2] = (__bf16)v.z; lv[2] = (__bf16)(v.z - (float)hv[2]);
            hv[3] = (__bf16)v.w; lv[3] = (__bf16)(v.w - (float)hv[3]);
            xh4[r * 192 + c] = hv;
            xl4[r * 192 + c] = lv;
        }
        #pragma unroll
        for (int off = 32; off > 0; off >>= 1) s += __shfl_down(s, off);
        if (lane == 0) avec[(size_t)b * SS + r] = s + b00;
    }
}

// ---------------- K3: GEMM1 MFMA 32x32x16, LDS layout [oct][row] (conflict-min) ----------------
// LDS 16B-slot s holds (oct = s>>7, row = s&127); staging inst (wave=oct, t): rows t*64+lane.
// Fragment read of 32 consecutive rows -> slot stride 1 -> bank stride 4 -> 4-way (b128 floor).
__global__ __launch_bounds__(256) void k_gemm1_mfma(const __bf16* __restrict__ Ah_g,
                                                    const __bf16* __restrict__ Al_g,
                                                    const __bf16* __restrict__ Bh_g,
                                                    const __bf16* __restrict__ Bl_g,
                                                    __bf16* __restrict__ Yh,
                                                    __bf16* __restrict__ Yl) {
    __shared__ __align__(16) __bf16 lds[4 * 4096];
    __bf16* As_h = lds;
    __bf16* As_l = lds + 4096;
    __bf16* Bs_h = lds + 8192;
    __bf16* Bs_l = lds + 12288;
    const int tid = threadIdx.x;
    const int wave = tid >> 6, lane = tid & 63;
    const int wy = wave >> 1, wx = wave & 1;
    const size_t m0 = (size_t)blockIdx.y * 128;
    const int n0 = blockIdx.x * 128;

    // staging rows (this wave stages k-oct = wave, i.e. global col kt + wave*8)
    const size_t gra0 = m0 + lane;        // t=0
    const size_t gra1 = m0 + 64 + lane;   // t=1
    const size_t grb0 = n0 + lane;
    const size_t grb1 = n0 + 64 + lane;
    const int lds_base = wave * 1024;     // elems = slot(wave*128)*8

    const int arow = wy * 64 + (lane & 31);
    const int brow = wx * 64 + (lane & 31);
    const int loct = lane >> 5;           // 0/1

    f32x16 acc[2][2] = {};
    for (int kt = 0; kt < HH; kt += 32) {
        const int gcol = kt + wave * 8;
        gld16(Ah_g + gra0 * HH + gcol, As_h + lds_base);
        gld16(Ah_g + gra1 * HH + gcol, As_h + lds_base + 512);
        gld16(Al_g + gra0 * HH + gcol, As_l + lds_base);
        gld16(Al_g + gra1 * HH + gcol, As_l + lds_base + 512);
        gld16(Bh_g + grb0 * HH + gcol, Bs_h + lds_base);
        gld16(Bh_g + grb1 * HH + gcol, Bs_h + lds_base + 512);
        gld16(Bl_g + grb0 * HH + gcol, Bs_l + lds_base);
        gld16(Bl_g + grb1 * HH + gcol, Bs_l + lds_base + 512);
        __syncthreads();
        #pragma unroll
        for (int kh = 0; kh < 2; ++kh) {
            const int ob = (kh * 2 + loct) * 1024;   // oct base in elems
            bf16x8 fah[2], fal[2], fbh[2], fbl[2];
            #pragma unroll
            for (int t = 0; t < 2; ++t) {
                fah[t] = *(const bf16x8*)(As_h + ob + (arow + t * 32) * 8);
                fal[t] = *(const bf16x8*)(As_l + ob + (arow + t * 32) * 8);
                fbh[t] = *(const bf16x8*)(Bs_h + ob + (brow + t * 32) * 8);
                fbl[t] = *(const bf16x8*)(Bs_l + ob + (brow + t * 32) * 8);
            }
            #pragma unroll
            for (int ti = 0; ti < 2; ++ti)
                #pragma unroll
                for (int tj = 0; tj < 2; ++tj) {
                    acc[ti][tj] = __builtin_amdgcn_mfma_f32_32x32x16_bf16(fal[ti], fbh[tj], acc[ti][tj], 0, 0, 0);
                    acc[ti][tj] = __builtin_amdgcn_mfma_f32_32x32x16_bf16(fah[ti], fbl[tj], acc[ti][tj], 0, 0, 0);
                    acc[ti][tj] = __builtin_amdgcn_mfma_f32_32x32x16_bf16(fah[ti], fbh[tj], acc[ti][tj], 0, 0, 0);
                }
        }
        __syncthreads();
    }
    // 32x32 C/D: col = lane&31, row = (reg&3) + 8*(reg>>2) + 4*(lane>>5)
    const int rbase = 4 * (lane >> 5);
    const int colb = lane & 31;
    #pragma unroll
    for (int ti = 0; ti < 2; ++ti) {
        #pragma unroll
        for (int tj = 0; tj < 2; ++tj) {
            int col = n0 + wx * 64 + tj * 32 + colb;
            #pragma unroll
            for (int r = 0; r < 16; ++r) {
                int row = wy * 64 + ti * 32 + (r & 3) + 8 * (r >> 2) + rbase;
                float v = acc[ti][tj][r];
                __bf16 hv = (__bf16)v;
                size_t idx = (m0 + row) * HH + col;
                Yh[idx] = hv;
                Yl[idx] = (__bf16)(v - (float)hv);
            }
        }
    }
}

// ---------------- K4: GEMM2 MFMA 32x32x16, [oct][row] LDS  q[b]=sigmoid(Y X^T + a) ----------------
__global__ __launch_bounds__(256) void k_gemm2_mfma(const __bf16* __restrict__ Yh,
                                                    const __bf16* __restrict__ Yl,
                                                    const __bf16* __restrict__ Xh,
                                                    const __bf16* __restrict__ Xl,
                                                    const float* __restrict__ avec,
                                                    float* __restrict__ q, int b_off) {
    __shared__ __align__(16) __bf16 lds[4 * 4096];
    __shared__ float av_s[SS];
    __bf16* As_h = lds;
    __bf16* As_l = lds + 4096;
    __bf16* Bs_h = lds + 8192;
    __bf16* Bs_l = lds + 12288;
    const int bl = blockIdx.x;
    const int b = b_off + bl;
    const __bf16* Ah_g = Yh + (size_t)bl * SS * HH;
    const __bf16* Al_g = Yl + (size_t)bl * SS * HH;
    const __bf16* Bh_g = Xh + (size_t)bl * SS * HH;
    const __bf16* Bl_g = Xl + (size_t)bl * SS * HH;
    const int tid = threadIdx.x;
    const int wave = tid >> 6, lane = tid & 63;
    const int wy = wave >> 1, wx = wave & 1;
    if (tid < SS) av_s[tid] = avec[(size_t)b * SS + tid];

    const size_t r0 = lane;                                       // t=0 rows < 100
    const size_t r1 = (64 + lane) < SS ? (64 + lane) : SS - 1;    // t=1 clamp
    const int lds_base = wave * 1024;

    const int arow = wy * 64 + (lane & 31);
    const int brow = wx * 64 + (lane & 31);
    const int loct = lane >> 5;

    f32x16 acc[2][2] = {};
    for (int kt = 0; kt < HH; kt += 32) {
        const int gcol = kt + wave * 8;
        gld16(Ah_g + r0 * HH + gcol, As_h + lds_base);
        gld16(Ah_g + r1 * HH + gcol, As_h + lds_base + 512);
        gld16(Al_g + r0 * HH + gcol, As_l + lds_base);
        gld16(Al_g + r1 * HH + gcol, As_l + lds_base + 512);
        gld16(Bh_g + r0 * HH + gcol, Bs_h + lds_base);
        gld16(Bh_g + r1 * HH + gcol, Bs_h + lds_base + 512);
        gld16(Bl_g + r0 * HH + gcol, Bs_l + lds_base);
        gld16(Bl_g + r1 * HH + gcol, Bs_l + lds_base + 512);
        __syncthreads();
        #pragma unroll
        for (int kh = 0; kh < 2; ++kh) {
            const int ob = (kh * 2 + loct) * 1024;
            bf16x8 fah[2], fal[2], fbh[2], fbl[2];
            #pragma unroll
            for (int t = 0; t < 2; ++t) {
                fah[t] = *(const bf16x8*)(As_h + ob + (arow + t * 32) * 8);
                fal[t] = *(const bf16x8*)(As_l + ob + (arow + t * 32) * 8);
                fbh[t] = *(const bf16x8*)(Bs_h + ob + (brow + t * 32) * 8);
                fbl[t] = *(const bf16x8*)(Bs_l + ob + (brow + t * 32) * 8);
            }
            #pragma unroll
            for (int ti = 0; ti < 2; ++ti)
                #pragma unroll
                for (int tj = 0; tj < 2; ++tj) {
                    acc[ti][tj] = __builtin_amdgcn_mfma_f32_32x32x16_bf16(fal[ti], fbh[tj], acc[ti][tj], 0, 0, 0);
                    acc[ti][tj] = __builtin_amdgcn_mfma_f32_32x32x16_bf16(fah[ti], fbl[tj], acc[ti][tj], 0, 0, 0);
                    acc[ti][tj] = __builtin_amdgcn_mfma_f32_32x32x16_bf16(fah[ti], fbh[tj], acc[ti][tj], 0, 0, 0);
                }
        }
        __syncthreads();
    }
    float* qb = q + (size_t)b * SS * SS;
    const int rbase = 4 * (lane >> 5);
    const int colb = lane & 31;
    #pragma unroll
    for (int ti = 0; ti < 2; ++ti) {
        #pragma unroll
        for (int tj = 0; tj < 2; ++tj) {
            int j = wx * 64 + tj * 32 + colb;
            if (j >= SS) continue;
            #pragma unroll
            for (int r = 0; r < 16; ++r) {
                int i = wy * 64 + ti * 32 + (r & 3) + 8 * (r >> 2) + rbase;
                if (i >= SS) continue;
                float v = acc[ti][tj][r] + av_s[i];
                qb[(size_t)i * SS + j] = 1.0f / (1.0f + __expf(-v));
            }
        }
    }
}

// ---------------- K5: colsum + fixed-point solve, M held in registers ----------------
__global__ __launch_bounds__(128) void k_solve(const float* __restrict__ q,
                                               float* __restrict__ out) {
    __shared__ __align__(16) float m[SS * SS];
    __shared__ __align__(16) float csinv[SS];
    __shared__ __align__(16) float x0[SS], x1[SS];
    int b = blockIdx.x, tid = threadIdx.x;
    const float* qb = q + (size_t)b * SS * SS;
    for (int e4 = tid; e4 < SS * SS / 4; e4 += 128)
        *(float4*)(m + e4 * 4) = *(const float4*)(qb + (size_t)e4 * 4);
    __syncthreads();
    if (tid < SS) {
        float s = 0.f;
        for (int i = 0; i < SS; ++i) s += m[i * SS + tid];
        csinv[tid] = 0.8f / s;
        x0[tid] = 1.0f / SS;
    }
    __syncthreads();
    float4 mreg[25];
    if (tid < SS) {
        #pragma unroll
        for (int j4 = 0; j4 < 25; ++j4) {
            float4 mv = *(const float4*)(m + tid * SS + j4 * 4);
            float4 cv = *(const float4*)(csinv + j4 * 4);
            mreg[j4].x = mv.x * cv.x;
            mreg[j4].y = mv.y * cv.y;
            mreg[j4].z = mv.z * cv.z;
            mreg[j4].w = mv.w * cv.w;
        }
    } else {
        #pragma unroll
        for (int j4 = 0; j4 < 25; ++j4) mreg[j4] = float4{0, 0, 0, 0};
    }
    __syncthreads();
    #pragma unroll 1
    for (int it = 0; it < 56; ++it) {
        const float* xr = (it & 1) ? x1 : x0;
        float* xw = (it & 1) ? x0 : x1;
        if (tid < SS) {
            float sx = 0.f, sy = 0.f, sz = 0.f, sw = 0.f;
            #pragma unroll
            for (int j4 = 0; j4 < 25; ++j4) {
                float4 xv = *(const float4*)(xr + j4 * 4);
                sx = fmaf(mreg[j4].x, xv.x, sx);
                sy = fmaf(mreg[j4].y, xv.y, sy);
                sz = fmaf(mreg[j4].z, xv.z, sz);
                sw = fmaf(mreg[j4].w, xv.w, sw);
            }
            xw[tid] = 0.002f + ((sx + sy) + (sz + sw));
        }
        __syncthreads();
    }
    if (tid < SS) out[(size_t)b * SS + tid] = x0[tid];
}

extern "C" void kernel_launch(void* const* d_in, const int* in_sizes, int n_in,
                              void* d_out, int out_size, void* d_ws, size_t ws_size,
                              hipStream_t stream) {
    (void)in_sizes; (void)n_in; (void)out_size;
    const float* X    = (const float*)d_in[0];
    const float* Wc   = (const float*)d_in[2];
    const float* Wsim = (const float*)d_in[3];
    const float* Wrel = (const float*)d_in[4];
    const float* bmat = (const float*)d_in[5];
    float* out = (float*)d_out;

    char* ws = (char*)d_ws;
    size_t off = 0;
    float*  qbuf = (float*)(ws + off);  off += (size_t)BB * SS * SS * 4;
    float*  drep = (float*)(ws + off);  off += (size_t)BB * HH * 4;
    float*  tmat = (float*)(ws + off);  off += (size_t)BB * HH * 4;
    float*  avec = (float*)(ws + off);  off += (size_t)BB * SS * 4;
    __bf16* Wth  = (__bf16*)(ws + off); off += (size_t)HH * HH * 2;
    __bf16* Wtl  = (__bf16*)(ws + off); off += (size_t)HH * HH * 2;

    int CB = 512;
    while (CB > 128 && off + 4 * (size_t)CB * SS * HH * 2 > ws_size) CB >>= 1;
    size_t xsz = (size_t)CB * SS * HH * 2;
    __bf16* Xh = (__bf16*)(ws + off); off += xsz;
    __bf16* Xl = (__bf16*)(ws + off); off += xsz;
    __bf16* Yh = (__bf16*)(ws + off); off += xsz;
    __bf16* Yl = (__bf16*)(ws + off); off += xsz;

    k_drep<<<dim3(BB, 3), 256, 0, stream>>>(X, drep);
    k_gemm_nt<<<dim3(HH / 64, BB / 64), 256, 0, stream>>>(drep, Wrel, tmat, HH, HH);
    k_splitw<<<dim3(HH / 32, HH / 32), 256, 0, stream>>>(Wsim, Wth, Wtl);

    for (int c = 0; c < BB; c += CB) {
        k_split_contrel<<<dim3(CB, 2), 512, 0, stream>>>(X + (size_t)c * SS * HH, Wc, tmat, bmat, Xh, Xl, avec, c);
        k_gemm1_mfma<<<dim3(HH / 128, CB * SS / 128), 256, 0, stream>>>(Xh, Xl, Wth, Wtl, Yh, Yl);
        k_gemm2_mfma<<<CB, 256, 0, stream>>>(Yh, Yl, Xh, Xl, avec, qbuf, c);
    }
    k_solve<<<BB, 128, 0, stream>>>(qbuf, out);
}

// Round 7
// 770.848 us; speedup vs baseline: 1.0754x; 1.0754x over previous
//
#include <hip/hip_runtime.h>
#include <math.h>

#define BB 512
#define SS 100
#define HH 768

typedef __bf16 bf16x8 __attribute__((ext_vector_type(8)));
typedef __bf16 bf16x4 __attribute__((ext_vector_type(4)));
typedef float f32x4 __attribute__((ext_vector_type(4)));
typedef float f32x16 __attribute__((ext_vector_type(16)));

__device__ __forceinline__ void gld16(const void* g, void* l) {
    __builtin_amdgcn_global_load_lds((const __attribute__((address_space(1))) char*)g,
                                     (__attribute__((address_space(3))) char*)l, 16, 0, 0);
}

// ---------------- K0: d_rep[b,h] = mean_s X[b,s,h]  (coalesced float4 col-reduce) ----------------
__global__ __launch_bounds__(256) void k_drep(const float* __restrict__ X,
                                              float* __restrict__ drep) {
    int b = blockIdx.x, g = blockIdx.y;
    int lane = threadIdx.x & 63, w = threadIdx.x >> 6;
    const float4* xb = (const float4*)(X + (size_t)b * SS * HH);
    int c4 = g * 64 + lane;
    float4 s = {0.f, 0.f, 0.f, 0.f};
    for (int r = w; r < SS; r += 4) {
        float4 v = xb[r * 192 + c4];
        s.x += v.x; s.y += v.y; s.z += v.z; s.w += v.w;
    }
    __shared__ float4 red[4][64];
    red[w][lane] = s;
    __syncthreads();
    if (w == 0) {
        float4 a0 = red[0][lane], a1 = red[1][lane], a2 = red[2][lane], a3 = red[3][lane];
        float4 o;
        o.x = (a0.x + a1.x + a2.x + a3.x) * (1.0f / SS);
        o.y = (a0.y + a1.y + a2.y + a3.y) * (1.0f / SS);
        o.z = (a0.z + a1.z + a2.z + a3.z) * (1.0f / SS);
        o.w = (a0.w + a1.w + a2.w + a3.w) * (1.0f / SS);
        ((float4*)(drep + (size_t)b * HH))[c4] = o;
    }
}

// ---------------- K1: t = d_rep @ W_rel^T  (fp32 NT, 64x64x16; 0.6 GFLOP) ----------------
__global__ __launch_bounds__(256) void k_gemm_nt(const float* __restrict__ A,
                                                 const float* __restrict__ Bm,
                                                 float* __restrict__ C,
                                                 int N, int K) {
    __shared__ float As[64 * 20];
    __shared__ float Bs[64 * 20];
    int tid = threadIdx.x;
    int ty = tid >> 4, tx = tid & 15;
    int m0 = blockIdx.y * 64, n0 = blockIdx.x * 64;
    int lr = tid >> 2, lc = (tid & 3) * 4;
    float acc[4][4] = {};
    for (int kt = 0; kt < K; kt += 16) {
        *(float4*)(As + lr * 20 + lc) = *(const float4*)(A + (size_t)(m0 + lr) * K + kt + lc);
        *(float4*)(Bs + lr * 20 + lc) = *(const float4*)(Bm + (size_t)(n0 + lr) * K + kt + lc);
        __syncthreads();
        #pragma unroll
        for (int k = 0; k < 16; k += 2) {
            float2 ar[4], br[4];
            #pragma unroll
            for (int ii = 0; ii < 4; ++ii) ar[ii] = *(const float2*)(As + (ty + 16 * ii) * 20 + k);
            #pragma unroll
            for (int jj = 0; jj < 4; ++jj) br[jj] = *(const float2*)(Bs + (tx + 16 * jj) * 20 + k);
            #pragma unroll
            for (int ii = 0; ii < 4; ++ii)
                #pragma unroll
                for (int jj = 0; jj < 4; ++jj)
                    acc[ii][jj] = fmaf(ar[ii].y, br[jj].y, fmaf(ar[ii].x, br[jj].x, acc[ii][jj]));
        }
        __syncthreads();
    }
    #pragma unroll
    for (int ii = 0; ii < 4; ++ii)
        #pragma unroll
        for (int jj = 0; jj < 4; ++jj)
            C[(size_t)(m0 + ty + 16 * ii) * N + n0 + tx + 16 * jj] = acc[ii][jj];
}

// ---------------- K_splitw: W(K x N) -> Wt_h/Wt_l (N x K) bf16 split ----------------
__global__ __launch_bounds__(256) void k_splitw(const float* __restrict__ W,
                                                __bf16* __restrict__ th,
                                                __bf16* __restrict__ tl) {
    __shared__ float tile[32][33];
    int bn = blockIdx.x * 32, bk = blockIdx.y * 32;
    int tx = threadIdx.x & 31, ty = threadIdx.x >> 5;
    for (int r = ty; r < 32; r += 8)
        tile[r][tx] = W[(size_t)(bk + r) * HH + bn + tx];
    __syncthreads();
    for (int r = ty; r < 32; r += 8) {
        float v = tile[tx][r];
        __bf16 hv = (__bf16)v;
        size_t idx = (size_t)(bn + r) * HH + bk + tx;
        th[idx] = hv;
        tl[idx] = (__bf16)(v - (float)hv);
    }
}

// ---------------- K_split+contrel: split X chunk to bf16 hi/lo AND a[b,i]=X[b,i]·u[b]+b00 ----------------
__global__ __launch_bounds__(512) void k_split_contrel(const float* __restrict__ X,
                                                       const float* __restrict__ Wc,
                                                       const float* __restrict__ tmat,
                                                       const float* __restrict__ bmat,
                                                       __bf16* __restrict__ Xh,
                                                       __bf16* __restrict__ Xl,
                                                       float* __restrict__ avec,
                                                       int b_off) {
    __shared__ float4 u4[192];
    int lb = blockIdx.x, half = blockIdx.y;
    int b = b_off + lb;
    int tid = threadIdx.x, lane = tid & 63, w = tid >> 6;
    for (int c = tid; c < 192; c += 512) {
        float4 wc = ((const float4*)Wc)[c];
        float4 tm = ((const float4*)(tmat + (size_t)b * HH))[c];
        float4 o = {wc.x + tm.x, wc.y + tm.y, wc.z + tm.z, wc.w + tm.w};
        u4[c] = o;
    }
    __syncthreads();
    float b00 = bmat[0];
    const float4* xb = (const float4*)(X + (size_t)b * SS * HH);
    bf16x4* xh4 = (bf16x4*)(Xh + (size_t)lb * SS * HH);
    bf16x4* xl4 = (bf16x4*)(Xl + (size_t)lb * SS * HH);
    int rend = half * 50 + 50;
    for (int r = half * 50 + w; r < rend; r += 8) {
        float s = 0.f;
        #pragma unroll
        for (int cc = 0; cc < 3; ++cc) {
            int c = cc * 64 + lane;
            float4 v = xb[r * 192 + c];
            float4 uu = u4[c];
            s = fmaf(v.x, uu.x, fmaf(v.y, uu.y, fmaf(v.z, uu.z, fmaf(v.w, uu.w, s))));
            bf16x4 hv, lv;
            hv[0] = (__bf16)v.x; lv[0] = (__bf16)(v.x - (float)hv[0]);
            hv[1] = (__bf16)v.y; lv[1] = (__bf16)(v.y - (float)hv[1]);
            hv[2] = (__bf16)v.z; lv[2] = (__bf16)(v.z - (float)hv[2]);
            hv[3] = (__bf16)v.w; lv[3] = (__bf16)(v.w - (float)hv[3]);
            xh4[r * 192 + c] = hv;
            xl4[r * 192 + c] = lv;
        }
        #pragma unroll
        for (int off = 32; off > 0; off >>= 1) s += __shfl_down(s, off);
        if (lane == 0) avec[(size_t)b * SS + r] = s + b00;
    }
}

// ---------------- K3: GEMM1 MFMA 32x32x16 ----------------
// Staging (coalesced + conflict-free): inst (wave w, t): lane l -> row w*32+t*16+(l&15),
// oct l>>4. Each row's 4 octs in one inst => 16 full 64B sectors. LDS slot(row,oct) =
// (row>>4)*64 + oct*16 + (row&15); fragment reads hit all 8 bank-groups evenly (0-conflict).
__global__ __launch_bounds__(256) void k_gemm1_mfma(const __bf16* __restrict__ Ah_g,
                                                    const __bf16* __restrict__ Al_g,
                                                    const __bf16* __restrict__ Bh_g,
                                                    const __bf16* __restrict__ Bl_g,
                                                    __bf16* __restrict__ Yh,
                                                    __bf16* __restrict__ Yl) {
    __shared__ __align__(16) __bf16 lds[4 * 4096];
    __bf16* As_h = lds;
    __bf16* As_l = lds + 4096;
    __bf16* Bs_h = lds + 8192;
    __bf16* Bs_l = lds + 12288;
    const int tid = threadIdx.x;
    const int wave = tid >> 6, lane = tid & 63;
    const int wy = wave >> 1, wx = wave & 1;
    const size_t m0 = (size_t)blockIdx.y * 128;
    const int n0 = blockIdx.x * 128;

    // staging: row = base + wave*32 + t*16 + (lane&15), col = kt + (lane>>4)*8
    const int srow = wave * 32 + (lane & 15);
    const int scol = (lane >> 4) * 8;
    const int lds_base = wave * 1024;          // elems; +512 for t=1

    // fragment base: elem = wy*2048 + t*1024 + r16*512 + (kh*2+loct)*128 + rlo*8
    const int rlo = lane & 15;
    const int r16 = (lane >> 4) & 1;
    const int loct = lane >> 5;
    const int fa = wy * 2048 + r16 * 512 + loct * 128 + rlo * 8;
    const int fb = wx * 2048 + r16 * 512 + loct * 128 + rlo * 8;

    f32x16 acc[2][2] = {};
    for (int kt = 0; kt < HH; kt += 32) {
        const int gcol = kt + scol;
        const size_t ga0 = (m0 + srow) * HH + gcol;
        const size_t ga1 = ga0 + (size_t)16 * HH;
        const size_t gb0 = (size_t)(n0 + srow) * HH + gcol;
        const size_t gb1 = gb0 + (size_t)16 * HH;
        gld16(Ah_g + ga0, As_h + lds_base);
        gld16(Ah_g + ga1, As_h + lds_base + 512);
        gld16(Al_g + ga0, As_l + lds_base);
        gld16(Al_g + ga1, As_l + lds_base + 512);
        gld16(Bh_g + gb0, Bs_h + lds_base);
        gld16(Bh_g + gb1, Bs_h + lds_base + 512);
        gld16(Bl_g + gb0, Bs_l + lds_base);
        gld16(Bl_g + gb1, Bs_l + lds_base + 512);
        __syncthreads();
        #pragma unroll
        for (int kh = 0; kh < 2; ++kh) {
            bf16x8 fah[2], fal[2], fbh[2], fbl[2];
            #pragma unroll
            for (int t = 0; t < 2; ++t) {
                const int oa = fa + t * 1024 + kh * 256;
                const int ob = fb + t * 1024 + kh * 256;
                fah[t] = *(const bf16x8*)(As_h + oa);
                fal[t] = *(const bf16x8*)(As_l + oa);
                fbh[t] = *(const bf16x8*)(Bs_h + ob);
                fbl[t] = *(const bf16x8*)(Bs_l + ob);
            }
            #pragma unroll
            for (int ti = 0; ti < 2; ++ti)
                #pragma unroll
                for (int tj = 0; tj < 2; ++tj) {
                    acc[ti][tj] = __builtin_amdgcn_mfma_f32_32x32x16_bf16(fal[ti], fbh[tj], acc[ti][tj], 0, 0, 0);
                    acc[ti][tj] = __builtin_amdgcn_mfma_f32_32x32x16_bf16(fah[ti], fbl[tj], acc[ti][tj], 0, 0, 0);
                    acc[ti][tj] = __builtin_amdgcn_mfma_f32_32x32x16_bf16(fah[ti], fbh[tj], acc[ti][tj], 0, 0, 0);
                }
        }
        __syncthreads();
    }
    // 32x32 C/D: col = lane&31, row = (reg&3) + 8*(reg>>2) + 4*(lane>>5)
    const int rbase = 4 * (lane >> 5);
    const int colb = lane & 31;
    #pragma unroll
    for (int ti = 0; ti < 2; ++ti) {
        #pragma unroll
        for (int tj = 0; tj < 2; ++tj) {
            int col = n0 + wx * 64 + tj * 32 + colb;
            #pragma unroll
            for (int r = 0; r < 16; ++r) {
                int row = wy * 64 + ti * 32 + (r & 3) + 8 * (r >> 2) + rbase;
                float v = acc[ti][tj][r];
                __bf16 hv = (__bf16)v;
                size_t idx = (m0 + row) * HH + col;
                Yh[idx] = hv;
                Yl[idx] = (__bf16)(v - (float)hv);
            }
        }
    }
}

// ---------------- K4: GEMM2 MFMA 32x32x16  q[b]=sigmoid(Y X^T + a), same layout ----------------
__global__ __launch_bounds__(256) void k_gemm2_mfma(const __bf16* __restrict__ Yh,
                                                    const __bf16* __restrict__ Yl,
                                                    const __bf16* __restrict__ Xh,
                                                    const __bf16* __restrict__ Xl,
                                                    const float* __restrict__ avec,
                                                    float* __restrict__ q, int b_off) {
    __shared__ __align__(16) __bf16 lds[4 * 4096];
    __shared__ float av_s[SS];
    __bf16* As_h = lds;
    __bf16* As_l = lds + 4096;
    __bf16* Bs_h = lds + 8192;
    __bf16* Bs_l = lds + 12288;
    const int bl = blockIdx.x;
    const int b = b_off + bl;
    const __bf16* Ah_g = Yh + (size_t)bl * SS * HH;
    const __bf16* Al_g = Yl + (size_t)bl * SS * HH;
    const __bf16* Bh_g = Xh + (size_t)bl * SS * HH;
    const __bf16* Bl_g = Xl + (size_t)bl * SS * HH;
    const int tid = threadIdx.x;
    const int wave = tid >> 6, lane = tid & 63;
    const int wy = wave >> 1, wx = wave & 1;
    if (tid < SS) av_s[tid] = avec[(size_t)b * SS + tid];

    const int srow_raw = wave * 32 + (lane & 15);
    const size_t r0 = srow_raw < SS ? srow_raw : SS - 1;
    const size_t r1 = (srow_raw + 16) < SS ? (srow_raw + 16) : SS - 1;
    const int scol = (lane >> 4) * 8;
    const int lds_base = wave * 1024;

    const int rlo = lane & 15;
    const int r16 = (lane >> 4) & 1;
    const int loct = lane >> 5;
    const int fa = wy * 2048 + r16 * 512 + loct * 128 + rlo * 8;
    const int fb = wx * 2048 + r16 * 512 + loct * 128 + rlo * 8;

    f32x16 acc[2][2] = {};
    for (int kt = 0; kt < HH; kt += 32) {
        const int gcol = kt + scol;
        gld16(Ah_g + r0 * HH + gcol, As_h + lds_base);
        gld16(Ah_g + r1 * HH + gcol, As_h + lds_base + 512);
        gld16(Al_g + r0 * HH + gcol, As_l + lds_base);
        gld16(Al_g + r1 * HH + gcol, As_l + lds_base + 512);
        gld16(Bh_g + r0 * HH + gcol, Bs_h + lds_base);
        gld16(Bh_g + r1 * HH + gcol, Bs_h + lds_base + 512);
        gld16(Bl_g + r0 * HH + gcol, Bs_l + lds_base);
        gld16(Bl_g + r1 * HH + gcol, Bs_l + lds_base + 512);
        __syncthreads();
        #pragma unroll
        for (int kh = 0; kh < 2; ++kh) {
            bf16x8 fah[2], fal[2], fbh[2], fbl[2];
            #pragma unroll
            for (int t = 0; t < 2; ++t) {
                const int oa = fa + t * 1024 + kh * 256;
                const int ob = fb + t * 1024 + kh * 256;
                fah[t] = *(const bf16x8*)(As_h + oa);
                fal[t] = *(const bf16x8*)(As_l + oa);
                fbh[t] = *(const bf16x8*)(Bs_h + ob);
                fbl[t] = *(const bf16x8*)(Bs_l + ob);
            }
            #pragma unroll
            for (int ti = 0; ti < 2; ++ti)
                #pragma unroll
                for (int tj = 0; tj < 2; ++tj) {
                    acc[ti][tj] = __builtin_amdgcn_mfma_f32_32x32x16_bf16(fal[ti], fbh[tj], acc[ti][tj], 0, 0, 0);
                    acc[ti][tj] = __builtin_amdgcn_mfma_f32_32x32x16_bf16(fah[ti], fbl[tj], acc[ti][tj], 0, 0, 0);
                    acc[ti][tj] = __builtin_amdgcn_mfma_f32_32x32x16_bf16(fah[ti], fbh[tj], acc[ti][tj], 0, 0, 0);
                }
        }
        __syncthreads();
    }
    float* qb = q + (size_t)b * SS * SS;
    const int rbase = 4 * (lane >> 5);
    const int colb = lane & 31;
    #pragma unroll
    for (int ti = 0; ti < 2; ++ti) {
        #pragma unroll
        for (int tj = 0; tj < 2; ++tj) {
            int j = wx * 64 + tj * 32 + colb;
            if (j >= SS) continue;
            #pragma unroll
            for (int r = 0; r < 16; ++r) {
                int i = wy * 64 + ti * 32 + (r & 3) + 8 * (r >> 2) + rbase;
                if (i >= SS) continue;
                float v = acc[ti][tj][r] + av_s[i];
                qb[(size_t)i * SS + j] = 1.0f / (1.0f + __expf(-v));
            }
        }
    }
}

// ---------------- K5: colsum + fixed-point solve, M held in registers ----------------
__global__ __launch_bounds__(128) void k_solve(const float* __restrict__ q,
                                               float* __restrict__ out) {
    __shared__ __align__(16) float m[SS * SS];
    __shared__ __align__(16) float csinv[SS];
    __shared__ __align__(16) float x0[SS], x1[SS];
    int b = blockIdx.x, tid = threadIdx.x;
    const float* qb = q + (size_t)b * SS * SS;
    for (int e4 = tid; e4 < SS * SS / 4; e4 += 128)
        *(float4*)(m + e4 * 4) = *(const float4*)(qb + (size_t)e4 * 4);
    __syncthreads();
    if (tid < SS) {
        float s = 0.f;
        for (int i = 0; i < SS; ++i) s += m[i * SS + tid];
        csinv[tid] = 0.8f / s;
        x0[tid] = 1.0f / SS;
    }
    __syncthreads();
    float4 mreg[25];
    if (tid < SS) {
        #pragma unroll
        for (int j4 = 0; j4 < 25; ++j4) {
            float4 mv = *(const float4*)(m + tid * SS + j4 * 4);
            float4 cv = *(const float4*)(csinv + j4 * 4);
            mreg[j4].x = mv.x * cv.x;
            mreg[j4].y = mv.y * cv.y;
            mreg[j4].z = mv.z * cv.z;
            mreg[j4].w = mv.w * cv.w;
        }
    } else {
        #pragma unroll
        for (int j4 = 0; j4 < 25; ++j4) mreg[j4] = float4{0, 0, 0, 0};
    }
    __syncthreads();
    #pragma unroll 1
    for (int it = 0; it < 56; ++it) {
        const float* xr = (it & 1) ? x1 : x0;
        float* xw = (it & 1) ? x0 : x1;
        if (tid < SS) {
            float sx = 0.f, sy = 0.f, sz = 0.f, sw = 0.f;
            #pragma unroll
            for (int j4 = 0; j4 < 25; ++j4) {
                float4 xv = *(const float4*)(xr + j4 * 4);
                sx = fmaf(mreg[j4].x, xv.x, sx);
                sy = fmaf(mreg[j4].y, xv.y, sy);
                sz = fmaf(mreg[j4].z, xv.z, sz);
                sw = fmaf(mreg[j4].w, xv.w, sw);
            }
            xw[tid] = 0.002f + ((sx + sy) + (sz + sw));
        }
        __syncthreads();
    }
    if (tid < SS) out[(size_t)b * SS + tid] = x0[tid];
}

extern "C" void kernel_launch(void* const* d_in, const int* in_sizes, int n_in,
                              void* d_out, int out_size, void* d_ws, size_t ws_size,
                              hipStream_t stream) {
    (void)in_sizes; (void)n_in; (void)out_size;
    const float* X    = (const float*)d_in[0];
    const float* Wc   = (const float*)d_in[2];
    const float* Wsim = (const float*)d_in[3];
    const float* Wrel = (const float*)d_in[4];
    const float* bmat = (const float*)d_in[5];
    float* out = (float*)d_out;

    char* ws = (char*)d_ws;
    size_t off = 0;
    float*  qbuf = (float*)(ws + off);  off += (size_t)BB * SS * SS * 4;
    float*  drep = (float*)(ws + off);  off += (size_t)BB * HH * 4;
    float*  tmat = (float*)(ws + off);  off += (size_t)BB * HH * 4;
    float*  avec = (float*)(ws + off);  off += (size_t)BB * SS * 4;
    __bf16* Wth  = (__bf16*)(ws + off); off += (size_t)HH * HH * 2;
    __bf16* Wtl  = (__bf16*)(ws + off); off += (size_t)HH * HH * 2;

    int CB = 512;
    while (CB > 128 && off + 4 * (size_t)CB * SS * HH * 2 > ws_size) CB >>= 1;
    size_t xsz = (size_t)CB * SS * HH * 2;
    __bf16* Xh = (__bf16*)(ws + off); off += xsz;
    __bf16* Xl = (__bf16*)(ws + off); off += xsz;
    __bf16* Yh = (__bf16*)(ws + off); off += xsz;
    __bf16* Yl = (__bf16*)(ws + off); off += xsz;

    k_drep<<<dim3(BB, 3), 256, 0, stream>>>(X, drep);
    k_gemm_nt<<<dim3(HH / 64, BB / 64), 256, 0, stream>>>(drep, Wrel, tmat, HH, HH);
    k_splitw<<<dim3(HH / 32, HH / 32), 256, 0, stream>>>(Wsim, Wth, Wtl);

    for (int c = 0; c < BB; c += CB) {
        k_split_contrel<<<dim3(CB, 2), 512, 0, stream>>>(X + (size_t)c * SS * HH, Wc, tmat, bmat, Xh, Xl, avec, c);
        k_gemm1_mfma<<<dim3(HH / 128, CB * SS / 128), 256, 0, stream>>>(Xh, Xl, Wth, Wtl, Yh, Yl);
        k_gemm2_mfma<<<CB, 256, 0, stream>>>(Yh, Yl, Xh, Xl, avec, qbuf, c);
    }
    k_solve<<<BB, 128, 0, stream>>>(qbuf, out);
}

// Round 8
// 753.369 us; speedup vs baseline: 1.1003x; 1.0232x over previous
//
#include <hip/hip_runtime.h>
#include <math.h>

#define BB 512
#define SS 100
#define HH 768

typedef __bf16 bf16x8 __attribute__((ext_vector_type(8)));
typedef __bf16 bf16x4 __attribute__((ext_vector_type(4)));
typedef float f32x4 __attribute__((ext_vector_type(4)));
typedef float f32x16 __attribute__((ext_vector_type(16)));

// ---------------- K0: d_rep[b,h] = mean_s X[b,s,h]  (coalesced float4 col-reduce) ----------------
__global__ __launch_bounds__(256) void k_drep(const float* __restrict__ X,
                                              float* __restrict__ drep) {
    int b = blockIdx.x, g = blockIdx.y;
    int lane = threadIdx.x & 63, w = threadIdx.x >> 6;
    const float4* xb = (const float4*)(X + (size_t)b * SS * HH);
    int c4 = g * 64 + lane;
    float4 s = {0.f, 0.f, 0.f, 0.f};
    for (int r = w; r < SS; r += 4) {
        float4 v = xb[r * 192 + c4];
        s.x += v.x; s.y += v.y; s.z += v.z; s.w += v.w;
    }
    __shared__ float4 red[4][64];
    red[w][lane] = s;
    __syncthreads();
    if (w == 0) {
        float4 a0 = red[0][lane], a1 = red[1][lane], a2 = red[2][lane], a3 = red[3][lane];
        float4 o;
        o.x = (a0.x + a1.x + a2.x + a3.x) * (1.0f / SS);
        o.y = (a0.y + a1.y + a2.y + a3.y) * (1.0f / SS);
        o.z = (a0.z + a1.z + a2.z + a3.z) * (1.0f / SS);
        o.w = (a0.w + a1.w + a2.w + a3.w) * (1.0f / SS);
        ((float4*)(drep + (size_t)b * HH))[c4] = o;
    }
}

// ---------------- K1: t = d_rep @ W_rel^T  (fp32 NT, 64x64x16; 0.6 GFLOP) ----------------
__global__ __launch_bounds__(256) void k_gemm_nt(const float* __restrict__ A,
                                                 const float* __restrict__ Bm,
                                                 float* __restrict__ C,
                                                 int N, int K) {
    __shared__ float As[64 * 20];
    __shared__ float Bs[64 * 20];
    int tid = threadIdx.x;
    int ty = tid >> 4, tx = tid & 15;
    int m0 = blockIdx.y * 64, n0 = blockIdx.x * 64;
    int lr = tid >> 2, lc = (tid & 3) * 4;
    float acc[4][4] = {};
    for (int kt = 0; kt < K; kt += 16) {
        *(float4*)(As + lr * 20 + lc) = *(const float4*)(A + (size_t)(m0 + lr) * K + kt + lc);
        *(float4*)(Bs + lr * 20 + lc) = *(const float4*)(Bm + (size_t)(n0 + lr) * K + kt + lc);
        __syncthreads();
        #pragma unroll
        for (int k = 0; k < 16; k += 2) {
            float2 ar[4], br[4];
            #pragma unroll
            for (int ii = 0; ii < 4; ++ii) ar[ii] = *(const float2*)(As + (ty + 16 * ii) * 20 + k);
            #pragma unroll
            for (int jj = 0; jj < 4; ++jj) br[jj] = *(const float2*)(Bs + (tx + 16 * jj) * 20 + k);
            #pragma unroll
            for (int ii = 0; ii < 4; ++ii)
                #pragma unroll
                for (int jj = 0; jj < 4; ++jj)
                    acc[ii][jj] = fmaf(ar[ii].y, br[jj].y, fmaf(ar[ii].x, br[jj].x, acc[ii][jj]));
        }
        __syncthreads();
    }
    #pragma unroll
    for (int ii = 0; ii < 4; ++ii)
        #pragma unroll
        for (int jj = 0; jj < 4; ++jj)
            C[(size_t)(m0 + ty + 16 * ii) * N + n0 + tx + 16 * jj] = acc[ii][jj];
}

// ---------------- K_splitw: W(K x N) -> Wt_h/Wt_l (N x K) bf16 split ----------------
__global__ __launch_bounds__(256) void k_splitw(const float* __restrict__ W,
                                                __bf16* __restrict__ th,
                                                __bf16* __restrict__ tl) {
    __shared__ float tile[32][33];
    int bn = blockIdx.x * 32, bk = blockIdx.y * 32;
    int tx = threadIdx.x & 31, ty = threadIdx.x >> 5;
    for (int r = ty; r < 32; r += 8)
        tile[r][tx] = W[(size_t)(bk + r) * HH + bn + tx];
    __syncthreads();
    for (int r = ty; r < 32; r += 8) {
        float v = tile[tx][r];
        __bf16 hv = (__bf16)v;
        size_t idx = (size_t)(bn + r) * HH + bk + tx;
        th[idx] = hv;
        tl[idx] = (__bf16)(v - (float)hv);
    }
}

// ---------------- K_split+contrel: split X chunk to bf16 hi/lo AND a[b,i]=X[b,i]·u[b]+b00 ----------------
__global__ __launch_bounds__(512) void k_split_contrel(const float* __restrict__ X,
                                                       const float* __restrict__ Wc,
                                                       const float* __restrict__ tmat,
                                                       const float* __restrict__ bmat,
                                                       __bf16* __restrict__ Xh,
                                                       __bf16* __restrict__ Xl,
                                                       float* __restrict__ avec,
                                                       int b_off) {
    __shared__ float4 u4[192];
    int lb = blockIdx.x, half = blockIdx.y;
    int b = b_off + lb;
    int tid = threadIdx.x, lane = tid & 63, w = tid >> 6;
    for (int c = tid; c < 192; c += 512) {
        float4 wc = ((const float4*)Wc)[c];
        float4 tm = ((const float4*)(tmat + (size_t)b * HH))[c];
        float4 o = {wc.x + tm.x, wc.y + tm.y, wc.z + tm.z, wc.w + tm.w};
        u4[c] = o;
    }
    __syncthreads();
    float b00 = bmat[0];
    const float4* xb = (const float4*)(X + (size_t)b * SS * HH);
    bf16x4* xh4 = (bf16x4*)(Xh + (size_t)lb * SS * HH);
    bf16x4* xl4 = (bf16x4*)(Xl + (size_t)lb * SS * HH);
    int rend = half * 50 + 50;
    for (int r = half * 50 + w; r < rend; r += 8) {
        float s = 0.f;
        #pragma unroll
        for (int cc = 0; cc < 3; ++cc) {
            int c = cc * 64 + lane;
            float4 v = xb[r * 192 + c];
            float4 uu = u4[c];
            s = fmaf(v.x, uu.x, fmaf(v.y, uu.y, fmaf(v.z, uu.z, fmaf(v.w, uu.w, s))));
            bf16x4 hv, lv;
            hv[0] = (__bf16)v.x; lv[0] = (__bf16)(v.x - (float)hv[0]);
            hv[1] = (__bf16)v.y; lv[1] = (__bf16)(v.y - (float)hv[1]);
            hv[2] = (__bf16)v.z; lv[2] = (__bf16)(v.z - (float)hv[2]);
            hv[3] = (__bf16)v.w; lv[3] = (__bf16)(v.w - (float)hv[3]);
            xh4[r * 192 + c] = hv;
            xl4[r * 192 + c] = lv;
        }
        #pragma unroll
        for (int off = 32; off > 0; off >>= 1) s += __shfl_down(s, off);
        if (lane == 0) avec[(size_t)b * SS + r] = s + b00;
    }
}

// ---------------- K3: GEMM1 MFMA 32x32x16, VGPR-staged, [oct][row] LDS ----------------
// Global loads: 4 consecutive lanes cover one row's 64B (perfect coalescing).
// LDS layout: 16B slot = oct*128 + row -> reads AND writes are bank-uniform (0 conflict).
// Next K-step's loads issued after barrier2 -> in flight during MFMA phase.
__global__ __launch_bounds__(256) void k_gemm1_mfma(const __bf16* __restrict__ Ah_g,
                                                    const __bf16* __restrict__ Al_g,
                                                    const __bf16* __restrict__ Bh_g,
                                                    const __bf16* __restrict__ Bl_g,
                                                    __bf16* __restrict__ Yh,
                                                    __bf16* __restrict__ Yl) {
    __shared__ __align__(16) __bf16 lds[4 * 4096];
    __bf16* As_h = lds;
    __bf16* As_l = lds + 4096;
    __bf16* Bs_h = lds + 8192;
    __bf16* Bs_l = lds + 12288;
    const int tid = threadIdx.x;
    const int wave = tid >> 6, lane = tid & 63;
    const int wy = wave >> 1, wx = wave & 1;
    const size_t m0 = (size_t)blockIdx.y * 128;
    const int n0 = blockIdx.x * 128;

    // staging: lane -> rows sr0/sr1, k-oct sc
    const int sr0 = wave * 32 + (lane >> 2);
    const int sr1 = sr0 + 16;
    const int sc  = lane & 3;
    const int wsl0 = sc * 1024 + sr0 * 8;   // LDS elem offsets
    const int wsl1 = sc * 1024 + sr1 * 8;
    const size_t ga0 = (m0 + sr0) * HH + sc * 8;   // + kt
    const size_t ga1 = (m0 + sr1) * HH + sc * 8;
    const size_t gb0 = (size_t)(n0 + sr0) * HH + sc * 8;
    const size_t gb1 = (size_t)(n0 + sr1) * HH + sc * 8;

    // fragment read bases (R6-proven [oct][row])
    const int arow = wy * 64 + (lane & 31);
    const int brow = wx * 64 + (lane & 31);
    const int loct = lane >> 5;

    f32x16 acc[2][2] = {};
    bf16x8 pah0, pah1, pal0, pal1, pbh0, pbh1, pbl0, pbl1;
    pah0 = *(const bf16x8*)(Ah_g + ga0); pah1 = *(const bf16x8*)(Ah_g + ga1);
    pal0 = *(const bf16x8*)(Al_g + ga0); pal1 = *(const bf16x8*)(Al_g + ga1);
    pbh0 = *(const bf16x8*)(Bh_g + gb0); pbh1 = *(const bf16x8*)(Bh_g + gb1);
    pbl0 = *(const bf16x8*)(Bl_g + gb0); pbl1 = *(const bf16x8*)(Bl_g + gb1);

    for (int kt = 0; kt < HH; kt += 32) {
        __syncthreads();   // previous MFMA-phase reads complete
        *(bf16x8*)(As_h + wsl0) = pah0; *(bf16x8*)(As_h + wsl1) = pah1;
        *(bf16x8*)(As_l + wsl0) = pal0; *(bf16x8*)(As_l + wsl1) = pal1;
        *(bf16x8*)(Bs_h + wsl0) = pbh0; *(bf16x8*)(Bs_h + wsl1) = pbh1;
        *(bf16x8*)(Bs_l + wsl0) = pbl0; *(bf16x8*)(Bs_l + wsl1) = pbl1;
        __syncthreads();   // writes visible
        int ktn = kt + 32; if (ktn >= HH) ktn = 0;   // harmless wrap reload
        pah0 = *(const bf16x8*)(Ah_g + ga0 + ktn); pah1 = *(const bf16x8*)(Ah_g + ga1 + ktn);
        pal0 = *(const bf16x8*)(Al_g + ga0 + ktn); pal1 = *(const bf16x8*)(Al_g + ga1 + ktn);
        pbh0 = *(const bf16x8*)(Bh_g + gb0 + ktn); pbh1 = *(const bf16x8*)(Bh_g + gb1 + ktn);
        pbl0 = *(const bf16x8*)(Bl_g + gb0 + ktn); pbl1 = *(const bf16x8*)(Bl_g + gb1 + ktn);
        #pragma unroll
        for (int kh = 0; kh < 2; ++kh) {
            const int ob = (kh * 2 + loct) * 1024;
            bf16x8 fah[2], fal[2], fbh[2], fbl[2];
            #pragma unroll
            for (int t = 0; t < 2; ++t) {
                const int oa = ob + (arow + t * 32) * 8;
                const int obb = ob + (brow + t * 32) * 8;
                fah[t] = *(const bf16x8*)(As_h + oa);
                fal[t] = *(const bf16x8*)(As_l + oa);
                fbh[t] = *(const bf16x8*)(Bs_h + obb);
                fbl[t] = *(const bf16x8*)(Bs_l + obb);
            }
            #pragma unroll
            for (int ti = 0; ti < 2; ++ti)
                #pragma unroll
                for (int tj = 0; tj < 2; ++tj) {
                    acc[ti][tj] = __builtin_amdgcn_mfma_f32_32x32x16_bf16(fal[ti], fbh[tj], acc[ti][tj], 0, 0, 0);
                    acc[ti][tj] = __builtin_amdgcn_mfma_f32_32x32x16_bf16(fah[ti], fbl[tj], acc[ti][tj], 0, 0, 0);
                    acc[ti][tj] = __builtin_amdgcn_mfma_f32_32x32x16_bf16(fah[ti], fbh[tj], acc[ti][tj], 0, 0, 0);
                }
        }
    }
    // 32x32 C/D: col = lane&31, row = (reg&3) + 8*(reg>>2) + 4*(lane>>5)
    const int rbase = 4 * (lane >> 5);
    const int colb = lane & 31;
    #pragma unroll
    for (int ti = 0; ti < 2; ++ti) {
        #pragma unroll
        for (int tj = 0; tj < 2; ++tj) {
            int col = n0 + wx * 64 + tj * 32 + colb;
            #pragma unroll
            for (int r = 0; r < 16; ++r) {
                int row = wy * 64 + ti * 32 + (r & 3) + 8 * (r >> 2) + rbase;
                float v = acc[ti][tj][r];
                __bf16 hv = (__bf16)v;
                size_t idx = (m0 + row) * HH + col;
                Yh[idx] = hv;
                Yl[idx] = (__bf16)(v - (float)hv);
            }
        }
    }
}

// ---------------- K4: GEMM2 MFMA 32x32x16, VGPR-staged, [oct][row] LDS ----------------
__global__ __launch_bounds__(256) void k_gemm2_mfma(const __bf16* __restrict__ Yh,
                                                    const __bf16* __restrict__ Yl,
                                                    const __bf16* __restrict__ Xh,
                                                    const __bf16* __restrict__ Xl,
                                                    const float* __restrict__ avec,
                                                    float* __restrict__ q, int b_off) {
    __shared__ __align__(16) __bf16 lds[4 * 4096];
    __shared__ float av_s[SS];
    __bf16* As_h = lds;
    __bf16* As_l = lds + 4096;
    __bf16* Bs_h = lds + 8192;
    __bf16* Bs_l = lds + 12288;
    const int bl = blockIdx.x;
    const int b = b_off + bl;
    const __bf16* Ah_g = Yh + (size_t)bl * SS * HH;
    const __bf16* Al_g = Yl + (size_t)bl * SS * HH;
    const __bf16* Bh_g = Xh + (size_t)bl * SS * HH;
    const __bf16* Bl_g = Xl + (size_t)bl * SS * HH;
    const int tid = threadIdx.x;
    const int wave = tid >> 6, lane = tid & 63;
    const int wy = wave >> 1, wx = wave & 1;
    if (tid < SS) av_s[tid] = avec[(size_t)b * SS + tid];

    const int sr0 = wave * 32 + (lane >> 2);
    const int sr1 = sr0 + 16;
    const int sc  = lane & 3;
    const int wsl0 = sc * 1024 + sr0 * 8;
    const int wsl1 = sc * 1024 + sr1 * 8;
    const int r0c = sr0 < SS ? sr0 : SS - 1;
    const int r1c = sr1 < SS ? sr1 : SS - 1;
    const size_t ga0 = (size_t)r0c * HH + sc * 8;
    const size_t ga1 = (size_t)r1c * HH + sc * 8;

    const int arow = wy * 64 + (lane & 31);
    const int brow = wx * 64 + (lane & 31);
    const int loct = lane >> 5;

    f32x16 acc[2][2] = {};
    bf16x8 pah0, pah1, pal0, pal1, pbh0, pbh1, pbl0, pbl1;
    pah0 = *(const bf16x8*)(Ah_g + ga0); pah1 = *(const bf16x8*)(Ah_g + ga1);
    pal0 = *(const bf16x8*)(Al_g + ga0); pal1 = *(const bf16x8*)(Al_g + ga1);
    pbh0 = *(const bf16x8*)(Bh_g + ga0); pbh1 = *(const bf16x8*)(Bh_g + ga1);
    pbl0 = *(const bf16x8*)(Bl_g + ga0); pbl1 = *(const bf16x8*)(Bl_g + ga1);

    for (int kt = 0; kt < HH; kt += 32) {
        __syncthreads();
        *(bf16x8*)(As_h + wsl0) = pah0; *(bf16x8*)(As_h + wsl1) = pah1;
        *(bf16x8*)(As_l + wsl0) = pal0; *(bf16x8*)(As_l + wsl1) = pal1;
        *(bf16x8*)(Bs_h + wsl0) = pbh0; *(bf16x8*)(Bs_h + wsl1) = pbh1;
        *(bf16x8*)(Bs_l + wsl0) = pbl0; *(bf16x8*)(Bs_l + wsl1) = pbl1;
        __syncthreads();
        int ktn = kt + 32; if (ktn >= HH) ktn = 0;
        pah0 = *(const bf16x8*)(Ah_g + ga0 + ktn); pah1 = *(const bf16x8*)(Ah_g + ga1 + ktn);
        pal0 = *(const bf16x8*)(Al_g + ga0 + ktn); pal1 = *(const bf16x8*)(Al_g + ga1 + ktn);
        pbh0 = *(const bf16x8*)(Bh_g + ga0 + ktn); pbh1 = *(const bf16x8*)(Bh_g + ga1 + ktn);
        pbl0 = *(const bf16x8*)(Bl_g + ga0 + ktn); pbl1 = *(const bf16x8*)(Bl_g + ga1 + ktn);
        #pragma unroll
        for (int kh = 0; kh < 2; ++kh) {
            const int ob = (kh * 2 + loct) * 1024;
            bf16x8 fah[2], fal[2], fbh[2], fbl[2];
            #pragma unroll
            for (int t = 0; t < 2; ++t) {
                const int oa = ob + (arow + t * 32) * 8;
                const int obb = ob + (brow + t * 32) * 8;
                fah[t] = *(const bf16x8*)(As_h + oa);
                fal[t] = *(const bf16x8*)(As_l + oa);
                fbh[t] = *(const bf16x8*)(Bs_h + obb);
                fbl[t] = *(const bf16x8*)(Bs_l + obb);
            }
            #pragma unroll
            for (int ti = 0; ti < 2; ++ti)
                #pragma unroll
                for (int tj = 0; tj < 2; ++tj) {
                    acc[ti][tj] = __builtin_amdgcn_mfma_f32_32x32x16_bf16(fal[ti], fbh[tj], acc[ti][tj], 0, 0, 0);
                    acc[ti][tj] = __builtin_amdgcn_mfma_f32_32x32x16_bf16(fah[ti], fbl[tj], acc[ti][tj], 0, 0, 0);
                    acc[ti][tj] = __builtin_amdgcn_mfma_f32_32x32x16_bf16(fah[ti], fbh[tj], acc[ti][tj], 0, 0, 0);
                }
        }
    }
    float* qb = q + (size_t)b * SS * SS;
    const int rbase = 4 * (lane >> 5);
    const int colb = lane & 31;
    #pragma unroll
    for (int ti = 0; ti < 2; ++ti) {
        #pragma unroll
        for (int tj = 0; tj < 2; ++tj) {
            int j = wx * 64 + tj * 32 + colb;
            if (j >= SS) continue;
            #pragma unroll
            for (int r = 0; r < 16; ++r) {
                int i = wy * 64 + ti * 32 + (r & 3) + 8 * (r >> 2) + rbase;
                if (i >= SS) continue;
                float v = acc[ti][tj][r] + av_s[i];
                qb[(size_t)i * SS + j] = 1.0f / (1.0f + __expf(-v));
            }
        }
    }
}

// ---------------- K5: colsum + fixed-point solve, M held in registers ----------------
__global__ __launch_bounds__(128) void k_solve(const float* __restrict__ q,
                                               float* __restrict__ out) {
    __shared__ __align__(16) float m[SS * SS];
    __shared__ __align__(16) float csinv[SS];
    __shared__ __align__(16) float x0[SS], x1[SS];
    int b = blockIdx.x, tid = threadIdx.x;
    const float* qb = q + (size_t)b * SS * SS;
    for (int e4 = tid; e4 < SS * SS / 4; e4 += 128)
        *(float4*)(m + e4 * 4) = *(const float4*)(qb + (size_t)e4 * 4);
    __syncthreads();
    if (tid < SS) {
        float s = 0.f;
        for (int i = 0; i < SS; ++i) s += m[i * SS + tid];
        csinv[tid] = 0.8f / s;
        x0[tid] = 1.0f / SS;
    }
    __syncthreads();
    float4 mreg[25];
    if (tid < SS) {
        #pragma unroll
        for (int j4 = 0; j4 < 25; ++j4) {
            float4 mv = *(const float4*)(m + tid * SS + j4 * 4);
            float4 cv = *(const float4*)(csinv + j4 * 4);
            mreg[j4].x = mv.x * cv.x;
            mreg[j4].y = mv.y * cv.y;
            mreg[j4].z = mv.z * cv.z;
            mreg[j4].w = mv.w * cv.w;
        }
    } else {
        #pragma unroll
        for (int j4 = 0; j4 < 25; ++j4) mreg[j4] = float4{0, 0, 0, 0};
    }
    __syncthreads();
    #pragma unroll 1
    for (int it = 0; it < 56; ++it) {
        const float* xr = (it & 1) ? x1 : x0;
        float* xw = (it & 1) ? x0 : x1;
        if (tid < SS) {
            float sx = 0.f, sy = 0.f, sz = 0.f, sw = 0.f;
            #pragma unroll
            for (int j4 = 0; j4 < 25; ++j4) {
                float4 xv = *(const float4*)(xr + j4 * 4);
                sx = fmaf(mreg[j4].x, xv.x, sx);
                sy = fmaf(mreg[j4].y, xv.y, sy);
                sz = fmaf(mreg[j4].z, xv.z, sz);
                sw = fmaf(mreg[j4].w, xv.w, sw);
            }
            xw[tid] = 0.002f + ((sx + sy) + (sz + sw));
        }
        __syncthreads();
    }
    if (tid < SS) out[(size_t)b * SS + tid] = x0[tid];
}

extern "C" void kernel_launch(void* const* d_in, const int* in_sizes, int n_in,
                              void* d_out, int out_size, void* d_ws, size_t ws_size,
                              hipStream_t stream) {
    (void)in_sizes; (void)n_in; (void)out_size;
    const float* X    = (const float*)d_in[0];
    const float* Wc   = (const float*)d_in[2];
    const float* Wsim = (const float*)d_in[3];
    const float* Wrel = (const float*)d_in[4];
    const float* bmat = (const float*)d_in[5];
    float* out = (float*)d_out;

    char* ws = (char*)d_ws;
    size_t off = 0;
    float*  qbuf = (float*)(ws + off);  off += (size_t)BB * SS * SS * 4;
    float*  drep = (float*)(ws + off);  off += (size_t)BB * HH * 4;
    float*  tmat = (float*)(ws + off);  off += (size_t)BB * HH * 4;
    float*  avec = (float*)(ws + off);  off += (size_t)BB * SS * 4;
    __bf16* Wth  = (__bf16*)(ws + off); off += (size_t)HH * HH * 2;
    __bf16* Wtl  = (__bf16*)(ws + off); off += (size_t)HH * HH * 2;

    int CB = 512;
    while (CB > 128 && off + 4 * (size_t)CB * SS * HH * 2 > ws_size) CB >>= 1;
    size_t xsz = (size_t)CB * SS * HH * 2;
    __bf16* Xh = (__bf16*)(ws + off); off += xsz;
    __bf16* Xl = (__bf16*)(ws + off); off += xsz;
    __bf16* Yh = (__bf16*)(ws + off); off += xsz;
    __bf16* Yl = (__bf16*)(ws + off); off += xsz;

    k_drep<<<dim3(BB, 3), 256, 0, stream>>>(X, drep);
    k_gemm_nt<<<dim3(HH / 64, BB / 64), 256, 0, stream>>>(drep, Wrel, tmat, HH, HH);
    k_splitw<<<dim3(HH / 32, HH / 32), 256, 0, stream>>>(Wsim, Wth, Wtl);

    for (int c = 0; c < BB; c += CB) {
        k_split_contrel<<<dim3(CB, 2), 512, 0, stream>>>(X + (size_t)c * SS * HH, Wc, tmat, bmat, Xh, Xl, avec, c);
        k_gemm1_mfma<<<dim3(HH / 128, CB * SS / 128), 256, 0, stream>>>(Xh, Xl, Wth, Wtl, Yh, Yl);
        k_gemm2_mfma<<<CB, 256, 0, stream>>>(Yh, Yl, Xh, Xl, avec, qbuf, c);
    }
    k_solve<<<BB, 128, 0, stream>>>(qbuf, out);
}

// Round 9
// 738.035 us; speedup vs baseline: 1.1232x; 1.0208x over previous
//
#include <hip/hip_runtime.h>
#include <math.h>

#define BB 512
#define SS 100
#define HH 768

typedef __bf16 bf16x8 __attribute__((ext_vector_type(8)));
typedef __bf16 bf16x4 __attribute__((ext_vector_type(4)));
typedef float f32x4 __attribute__((ext_vector_type(4)));
typedef float f32x16 __attribute__((ext_vector_type(16)));

// LDS 16B-slot placement for (row, oct): P = row*4 + ((oct + (row>>1)) & 3).
// Under the 8-lane-issue-group model (measured R5/R6/R7: 24 extra cyc/write when a
// group hits 2 quads; 0 when 8), both the coalesced write pattern (2 rows x 4 octs
// per group) and the fragment read pattern (8 rows x 1 oct) cover 8 distinct
// bank-quads -> 0 conflicts, while keeping 4-lanes-per-row global coalescing.
__device__ __forceinline__ int ldsSlot(int row, int oct) {
    return (row * 4 + ((oct + (row >> 1)) & 3)) * 8;   // __bf16 elem offset
}

// ---------------- K0: d_rep[b,h] = mean_s X[b,s,h]  (coalesced float4 col-reduce) ----------------
__global__ __launch_bounds__(256) void k_drep(const float* __restrict__ X,
                                              float* __restrict__ drep) {
    int b = blockIdx.x, g = blockIdx.y;
    int lane = threadIdx.x & 63, w = threadIdx.x >> 6;
    const float4* xb = (const float4*)(X + (size_t)b * SS * HH);
    int c4 = g * 64 + lane;
    float4 s = {0.f, 0.f, 0.f, 0.f};
    for (int r = w; r < SS; r += 4) {
        float4 v = xb[r * 192 + c4];
        s.x += v.x; s.y += v.y; s.z += v.z; s.w += v.w;
    }
    __shared__ float4 red[4][64];
    red[w][lane] = s;
    __syncthreads();
    if (w == 0) {
        float4 a0 = red[0][lane], a1 = red[1][lane], a2 = red[2][lane], a3 = red[3][lane];
        float4 o;
        o.x = (a0.x + a1.x + a2.x + a3.x) * (1.0f / SS);
        o.y = (a0.y + a1.y + a2.y + a3.y) * (1.0f / SS);
        o.z = (a0.z + a1.z + a2.z + a3.z) * (1.0f / SS);
        o.w = (a0.w + a1.w + a2.w + a3.w) * (1.0f / SS);
        ((float4*)(drep + (size_t)b * HH))[c4] = o;
    }
}

// ---------------- K1: t = d_rep @ W_rel^T  (fp32 NT, 64x64x16; 0.6 GFLOP) ----------------
__global__ __launch_bounds__(256) void k_gemm_nt(const float* __restrict__ A,
                                                 const float* __restrict__ Bm,
                                                 float* __restrict__ C,
                                                 int N, int K) {
    __shared__ float As[64 * 20];
    __shared__ float Bs[64 * 20];
    int tid = threadIdx.x;
    int ty = tid >> 4, tx = tid & 15;
    int m0 = blockIdx.y * 64, n0 = blockIdx.x * 64;
    int lr = tid >> 2, lc = (tid & 3) * 4;
    float acc[4][4] = {};
    for (int kt = 0; kt < K; kt += 16) {
        *(float4*)(As + lr * 20 + lc) = *(const float4*)(A + (size_t)(m0 + lr) * K + kt + lc);
        *(float4*)(Bs + lr * 20 + lc) = *(const float4*)(Bm + (size_t)(n0 + lr) * K + kt + lc);
        __syncthreads();
        #pragma unroll
        for (int k = 0; k < 16; k += 2) {
            float2 ar[4], br[4];
            #pragma unroll
            for (int ii = 0; ii < 4; ++ii) ar[ii] = *(const float2*)(As + (ty + 16 * ii) * 20 + k);
            #pragma unroll
            for (int jj = 0; jj < 4; ++jj) br[jj] = *(const float2*)(Bs + (tx + 16 * jj) * 20 + k);
            #pragma unroll
            for (int ii = 0; ii < 4; ++ii)
                #pragma unroll
                for (int jj = 0; jj < 4; ++jj)
                    acc[ii][jj] = fmaf(ar[ii].y, br[jj].y, fmaf(ar[ii].x, br[jj].x, acc[ii][jj]));
        }
        __syncthreads();
    }
    #pragma unroll
    for (int ii = 0; ii < 4; ++ii)
        #pragma unroll
        for (int jj = 0; jj < 4; ++jj)
            C[(size_t)(m0 + ty + 16 * ii) * N + n0 + tx + 16 * jj] = acc[ii][jj];
}

// ---------------- K_splitw: W(K x N) -> Wt_h/Wt_l (N x K) bf16 split ----------------
__global__ __launch_bounds__(256) void k_splitw(const float* __restrict__ W,
                                                __bf16* __restrict__ th,
                                                __bf16* __restrict__ tl) {
    __shared__ float tile[32][33];
    int bn = blockIdx.x * 32, bk = blockIdx.y * 32;
    int tx = threadIdx.x & 31, ty = threadIdx.x >> 5;
    for (int r = ty; r < 32; r += 8)
        tile[r][tx] = W[(size_t)(bk + r) * HH + bn + tx];
    __syncthreads();
    for (int r = ty; r < 32; r += 8) {
        float v = tile[tx][r];
        __bf16 hv = (__bf16)v;
        size_t idx = (size_t)(bn + r) * HH + bk + tx;
        th[idx] = hv;
        tl[idx] = (__bf16)(v - (float)hv);
    }
}

// ---------------- K_split+contrel: split X chunk to bf16 hi/lo AND a[b,i]=X[b,i]·u[b]+b00 ----------------
__global__ __launch_bounds__(512) void k_split_contrel(const float* __restrict__ X,
                                                       const float* __restrict__ Wc,
                                                       const float* __restrict__ tmat,
                                                       const float* __restrict__ bmat,
                                                       __bf16* __restrict__ Xh,
                                                       __bf16* __restrict__ Xl,
                                                       float* __restrict__ avec,
                                                       int b_off) {
    __shared__ float4 u4[192];
    int lb = blockIdx.x, half = blockIdx.y;
    int b = b_off + lb;
    int tid = threadIdx.x, lane = tid & 63, w = tid >> 6;
    for (int c = tid; c < 192; c += 512) {
        float4 wc = ((const float4*)Wc)[c];
        float4 tm = ((const float4*)(tmat + (size_t)b * HH))[c];
        float4 o = {wc.x + tm.x, wc.y + tm.y, wc.z + tm.z, wc.w + tm.w};
        u4[c] = o;
    }
    __syncthreads();
    float b00 = bmat[0];
    const float4* xb = (const float4*)(X + (size_t)b * SS * HH);
    bf16x4* xh4 = (bf16x4*)(Xh + (size_t)lb * SS * HH);
    bf16x4* xl4 = (bf16x4*)(Xl + (size_t)lb * SS * HH);
    int rend = half * 50 + 50;
    for (int r = half * 50 + w; r < rend; r += 8) {
        float s = 0.f;
        #pragma unroll
        for (int cc = 0; cc < 3; ++cc) {
            int c = cc * 64 + lane;
            float4 v = xb[r * 192 + c];
            float4 uu = u4[c];
            s = fmaf(v.x, uu.x, fmaf(v.y, uu.y, fmaf(v.z, uu.z, fmaf(v.w, uu.w, s))));
            bf16x4 hv, lv;
            hv[0] = (__bf16)v.x; lv[0] = (__bf16)(v.x - (float)hv[0]);
            hv[1] = (__bf16)v.y; lv[1] = (__bf16)(v.y - (float)hv[1]);
            hv[2] = (__bf16)v.z; lv[2] = (__bf16)(v.z - (float)hv[2]);
            hv[3] = (__bf16)v.w; lv[3] = (__bf16)(v.w - (float)hv[3]);
            xh4[r * 192 + c] = hv;
            xl4[r * 192 + c] = lv;
        }
        #pragma unroll
        for (int off = 32; off > 0; off >>= 1) s += __shfl_down(s, off);
        if (lane == 0) avec[(size_t)b * SS + r] = s + b00;
    }
}

// ---------------- K3: GEMM1 MFMA 32x32x16, VGPR-staged, swizzled LDS ----------------
__global__ __launch_bounds__(256) void k_gemm1_mfma(const __bf16* __restrict__ Ah_g,
                                                    const __bf16* __restrict__ Al_g,
                                                    const __bf16* __restrict__ Bh_g,
                                                    const __bf16* __restrict__ Bl_g,
                                                    __bf16* __restrict__ Yh,
                                                    __bf16* __restrict__ Yl) {
    __shared__ __align__(16) __bf16 lds[4 * 4096];
    __bf16* As_h = lds;
    __bf16* As_l = lds + 4096;
    __bf16* Bs_h = lds + 8192;
    __bf16* Bs_l = lds + 12288;
    const int tid = threadIdx.x;
    const int wave = tid >> 6, lane = tid & 63;
    const int wy = wave >> 1, wx = wave & 1;
    const size_t m0 = (size_t)blockIdx.y * 128;
    const int n0 = blockIdx.x * 128;

    // staging: lane -> rows sr0/sr1, k-oct sc (4 lanes cover one row's 64B)
    const int sr0 = wave * 32 + (lane >> 2);
    const int sr1 = sr0 + 16;
    const int sc  = lane & 3;
    const int wsl0 = ldsSlot(sr0, sc);
    const int wsl1 = ldsSlot(sr1, sc);
    const size_t ga0 = (m0 + sr0) * HH + sc * 8;   // + kt
    const size_t ga1 = (m0 + sr1) * HH + sc * 8;
    const size_t gb0 = (size_t)(n0 + sr0) * HH + sc * 8;
    const size_t gb1 = (size_t)(n0 + sr1) * HH + sc * 8;

    // fragment LDS offsets (kt-invariant): [kh][t]
    const int arow = wy * 64 + (lane & 31);
    const int brow = wx * 64 + (lane & 31);
    const int loct = lane >> 5;
    int offA[2][2], offB[2][2];
    #pragma unroll
    for (int kh = 0; kh < 2; ++kh)
        #pragma unroll
        for (int t = 0; t < 2; ++t) {
            offA[kh][t] = ldsSlot(arow + t * 32, kh * 2 + loct);
            offB[kh][t] = ldsSlot(brow + t * 32, kh * 2 + loct);
        }

    f32x16 acc[2][2] = {};
    bf16x8 pah0, pah1, pal0, pal1, pbh0, pbh1, pbl0, pbl1;
    pah0 = *(const bf16x8*)(Ah_g + ga0); pah1 = *(const bf16x8*)(Ah_g + ga1);
    pal0 = *(const bf16x8*)(Al_g + ga0); pal1 = *(const bf16x8*)(Al_g + ga1);
    pbh0 = *(const bf16x8*)(Bh_g + gb0); pbh1 = *(const bf16x8*)(Bh_g + gb1);
    pbl0 = *(const bf16x8*)(Bl_g + gb0); pbl1 = *(const bf16x8*)(Bl_g + gb1);

    for (int kt = 0; kt < HH; kt += 32) {
        __syncthreads();   // previous MFMA-phase reads complete
        *(bf16x8*)(As_h + wsl0) = pah0; *(bf16x8*)(As_h + wsl1) = pah1;
        *(bf16x8*)(As_l + wsl0) = pal0; *(bf16x8*)(As_l + wsl1) = pal1;
        *(bf16x8*)(Bs_h + wsl0) = pbh0; *(bf16x8*)(Bs_h + wsl1) = pbh1;
        *(bf16x8*)(Bs_l + wsl0) = pbl0; *(bf16x8*)(Bs_l + wsl1) = pbl1;
        __syncthreads();   // writes visible
        int ktn = kt + 32; if (ktn >= HH) ktn = 0;   // harmless wrap reload
        pah0 = *(const bf16x8*)(Ah_g + ga0 + ktn); pah1 = *(const bf16x8*)(Ah_g + ga1 + ktn);
        pal0 = *(const bf16x8*)(Al_g + ga0 + ktn); pal1 = *(const bf16x8*)(Al_g + ga1 + ktn);
        pbh0 = *(const bf16x8*)(Bh_g + gb0 + ktn); pbh1 = *(const bf16x8*)(Bh_g + gb1 + ktn);
        pbl0 = *(const bf16x8*)(Bl_g + gb0 + ktn); pbl1 = *(const bf16x8*)(Bl_g + gb1 + ktn);
        #pragma unroll
        for (int kh = 0; kh < 2; ++kh) {
            bf16x8 fah[2], fal[2], fbh[2], fbl[2];
            #pragma unroll
            for (int t = 0; t < 2; ++t) {
                fah[t] = *(const bf16x8*)(As_h + offA[kh][t]);
                fal[t] = *(const bf16x8*)(As_l + offA[kh][t]);
                fbh[t] = *(const bf16x8*)(Bs_h + offB[kh][t]);
                fbl[t] = *(const bf16x8*)(Bs_l + offB[kh][t]);
            }
            #pragma unroll
            for (int ti = 0; ti < 2; ++ti)
                #pragma unroll
                for (int tj = 0; tj < 2; ++tj) {
                    acc[ti][tj] = __builtin_amdgcn_mfma_f32_32x32x16_bf16(fal[ti], fbh[tj], acc[ti][tj], 0, 0, 0);
                    acc[ti][tj] = __builtin_amdgcn_mfma_f32_32x32x16_bf16(fah[ti], fbl[tj], acc[ti][tj], 0, 0, 0);
                    acc[ti][tj] = __builtin_amdgcn_mfma_f32_32x32x16_bf16(fah[ti], fbh[tj], acc[ti][tj], 0, 0, 0);
                }
        }
    }
    // 32x32 C/D: col = lane&31, row = (reg&3) + 8*(reg>>2) + 4*(lane>>5)
    const int rbase = 4 * (lane >> 5);
    const int colb = lane & 31;
    #pragma unroll
    for (int ti = 0; ti < 2; ++ti) {
        #pragma unroll
        for (int tj = 0; tj < 2; ++tj) {
            int col = n0 + wx * 64 + tj * 32 + colb;
            #pragma unroll
            for (int r = 0; r < 16; ++r) {
                int row = wy * 64 + ti * 32 + (r & 3) + 8 * (r >> 2) + rbase;
                float v = acc[ti][tj][r];
                __bf16 hv = (__bf16)v;
                size_t idx = (m0 + row) * HH + col;
                Yh[idx] = hv;
                Yl[idx] = (__bf16)(v - (float)hv);
            }
        }
    }
}

// ---------------- K4: GEMM2 MFMA 32x32x16, VGPR-staged, swizzled LDS ----------------
__global__ __launch_bounds__(256) void k_gemm2_mfma(const __bf16* __restrict__ Yh,
                                                    const __bf16* __restrict__ Yl,
                                                    const __bf16* __restrict__ Xh,
                                                    const __bf16* __restrict__ Xl,
                                                    const float* __restrict__ avec,
                                                    float* __restrict__ q, int b_off) {
    __shared__ __align__(16) __bf16 lds[4 * 4096];
    __shared__ float av_s[SS];
    __bf16* As_h = lds;
    __bf16* As_l = lds + 4096;
    __bf16* Bs_h = lds + 8192;
    __bf16* Bs_l = lds + 12288;
    const int bl = blockIdx.x;
    const int b = b_off + bl;
    const __bf16* Ah_g = Yh + (size_t)bl * SS * HH;
    const __bf16* Al_g = Yl + (size_t)bl * SS * HH;
    const __bf16* Bh_g = Xh + (size_t)bl * SS * HH;
    const __bf16* Bl_g = Xl + (size_t)bl * SS * HH;
    const int tid = threadIdx.x;
    const int wave = tid >> 6, lane = tid & 63;
    const int wy = wave >> 1, wx = wave & 1;
    if (tid < SS) av_s[tid] = avec[(size_t)b * SS + tid];

    const int sr0 = wave * 32 + (lane >> 2);
    const int sr1 = sr0 + 16;
    const int sc  = lane & 3;
    const int wsl0 = ldsSlot(sr0, sc);
    const int wsl1 = ldsSlot(sr1, sc);
    const int r0c = sr0 < SS ? sr0 : SS - 1;
    const int r1c = sr1 < SS ? sr1 : SS - 1;
    const size_t ga0 = (size_t)r0c * HH + sc * 8;
    const size_t ga1 = (size_t)r1c * HH + sc * 8;

    const int arow = wy * 64 + (lane & 31);
    const int brow = wx * 64 + (lane & 31);
    const int loct = lane >> 5;
    int offA[2][2], offB[2][2];
    #pragma unroll
    for (int kh = 0; kh < 2; ++kh)
        #pragma unroll
        for (int t = 0; t < 2; ++t) {
            offA[kh][t] = ldsSlot(arow + t * 32, kh * 2 + loct);
            offB[kh][t] = ldsSlot(brow + t * 32, kh * 2 + loct);
        }

    f32x16 acc[2][2] = {};
    bf16x8 pah0, pah1, pal0, pal1, pbh0, pbh1, pbl0, pbl1;
    pah0 = *(const bf16x8*)(Ah_g + ga0); pah1 = *(const bf16x8*)(Ah_g + ga1);
    pal0 = *(const bf16x8*)(Al_g + ga0); pal1 = *(const bf16x8*)(Al_g + ga1);
    pbh0 = *(const bf16x8*)(Bh_g + ga0); pbh1 = *(const bf16x8*)(Bh_g + ga1);
    pbl0 = *(const bf16x8*)(Bl_g + ga0); pbl1 = *(const bf16x8*)(Bl_g + ga1);

    for (int kt = 0; kt < HH; kt += 32) {
        __syncthreads();
        *(bf16x8*)(As_h + wsl0) = pah0; *(bf16x8*)(As_h + wsl1) = pah1;
        *(bf16x8*)(As_l + wsl0) = pal0; *(bf16x8*)(As_l + wsl1) = pal1;
        *(bf16x8*)(Bs_h + wsl0) = pbh0; *(bf16x8*)(Bs_h + wsl1) = pbh1;
        *(bf16x8*)(Bs_l + wsl0) = pbl0; *(bf16x8*)(Bs_l + wsl1) = pbl1;
        __syncthreads();
        int ktn = kt + 32; if (ktn >= HH) ktn = 0;
        pah0 = *(const bf16x8*)(Ah_g + ga0 + ktn); pah1 = *(const bf16x8*)(Ah_g + ga1 + ktn);
        pal0 = *(const bf16x8*)(Al_g + ga0 + ktn); pal1 = *(const bf16x8*)(Al_g + ga1 + ktn);
        pbh0 = *(const bf16x8*)(Bh_g + ga0 + ktn); pbh1 = *(const bf16x8*)(Bh_g + ga1 + ktn);
        pbl0 = *(const bf16x8*)(Bl_g + ga0 + ktn); pbl1 = *(const bf16x8*)(Bl_g + ga1 + ktn);
        #pragma unroll
        for (int kh = 0; kh < 2; ++kh) {
            bf16x8 fah[2], fal[2], fbh[2], fbl[2];
            #pragma unroll
            for (int t = 0; t < 2; ++t) {
                fah[t] = *(const bf16x8*)(As_h + offA[kh][t]);
                fal[t] = *(const bf16x8*)(As_l + offA[kh][t]);
                fbh[t] = *(const bf16x8*)(Bs_h + offB[kh][t]);
                fbl[t] = *(const bf16x8*)(Bs_l + offB[kh][t]);
            }
            #pragma unroll
            for (int ti = 0; ti < 2; ++ti)
                #pragma unroll
                for (int tj = 0; tj < 2; ++tj) {
                    acc[ti][tj] = __builtin_amdgcn_mfma_f32_32x32x16_bf16(fal[ti], fbh[tj], acc[ti][tj], 0, 0, 0);
                    acc[ti][tj] = __builtin_amdgcn_mfma_f32_32x32x16_bf16(fah[ti], fbl[tj], acc[ti][tj], 0, 0, 0);
                    acc[ti][tj] = __builtin_amdgcn_mfma_f32_32x32x16_bf16(fah[ti], fbh[tj], acc[ti][tj], 0, 0, 0);
                }
        }
    }
    float* qb = q + (size_t)b * SS * SS;
    const int rbase = 4 * (lane >> 5);
    const int colb = lane & 31;
    #pragma unroll
    for (int ti = 0; ti < 2; ++ti) {
        #pragma unroll
        for (int tj = 0; tj < 2; ++tj) {
            int j = wx * 64 + tj * 32 + colb;
            if (j >= SS) continue;
            #pragma unroll
            for (int r = 0; r < 16; ++r) {
                int i = wy * 64 + ti * 32 + (r & 3) + 8 * (r >> 2) + rbase;
                if (i >= SS) continue;
                float v = acc[ti][tj][r] + av_s[i];
                qb[(size_t)i * SS + j] = 1.0f / (1.0f + __expf(-v));
            }
        }
    }
}

// ---------------- K5: colsum + fixed-point solve, M held in registers ----------------
__global__ __launch_bounds__(128) void k_solve(const float* __restrict__ q,
                                               float* __restrict__ out) {
    __shared__ __align__(16) float m[SS * SS];
    __shared__ __align__(16) float csinv[SS];
    __shared__ __align__(16) float x0[SS], x1[SS];
    int b = blockIdx.x, tid = threadIdx.x;
    const float* qb = q + (size_t)b * SS * SS;
    for (int e4 = tid; e4 < SS * SS / 4; e4 += 128)
        *(float4*)(m + e4 * 4) = *(const float4*)(qb + (size_t)e4 * 4);
    __syncthreads();
    if (tid < SS) {
        float s = 0.f;
        for (int i = 0; i < SS; ++i) s += m[i * SS + tid];
        csinv[tid] = 0.8f / s;
        x0[tid] = 1.0f / SS;
    }
    __syncthreads();
    float4 mreg[25];
    if (tid < SS) {
        #pragma unroll
        for (int j4 = 0; j4 < 25; ++j4) {
            float4 mv = *(const float4*)(m + tid * SS + j4 * 4);
            float4 cv = *(const float4*)(csinv + j4 * 4);
            mreg[j4].x = mv.x * cv.x;
            mreg[j4].y = mv.y * cv.y;
            mreg[j4].z = mv.z * cv.z;
            mreg[j4].w = mv.w * cv.w;
        }
    } else {
        #pragma unroll
        for (int j4 = 0; j4 < 25; ++j4) mreg[j4] = float4{0, 0, 0, 0};
    }
    __syncthreads();
    #pragma unroll 1
    for (int it = 0; it < 56; ++it) {
        const float* xr = (it & 1) ? x1 : x0;
        float* xw = (it & 1) ? x0 : x1;
        if (tid < SS) {
            float sx = 0.f, sy = 0.f, sz = 0.f, sw = 0.f;
            #pragma unroll
            for (int j4 = 0; j4 < 25; ++j4) {
                float4 xv = *(const float4*)(xr + j4 * 4);
                sx = fmaf(mreg[j4].x, xv.x, sx);
                sy = fmaf(mreg[j4].y, xv.y, sy);
                sz = fmaf(mreg[j4].z, xv.z, sz);
                sw = fmaf(mreg[j4].w, xv.w, sw);
            }
            xw[tid] = 0.002f + ((sx + sy) + (sz + sw));
        }
        __syncthreads();
    }
    if (tid < SS) out[(size_t)b * SS + tid] = x0[tid];
}

extern "C" void kernel_launch(void* const* d_in, const int* in_sizes, int n_in,
                              void* d_out, int out_size, void* d_ws, size_t ws_size,
                              hipStream_t stream) {
    (void)in_sizes; (void)n_in; (void)out_size;
    const float* X    = (const float*)d_in[0];
    const float* Wc   = (const float*)d_in[2];
    const float* Wsim = (const float*)d_in[3];
    const float* Wrel = (const float*)d_in[4];
    const float* bmat = (const float*)d_in[5];
    float* out = (float*)d_out;

    char* ws = (char*)d_ws;
    size_t off = 0;
    float*  qbuf = (float*)(ws + off);  off += (size_t)BB * SS * SS * 4;
    float*  drep = (float*)(ws + off);  off += (size_t)BB * HH * 4;
    float*  tmat = (float*)(ws + off);  off += (size_t)BB * HH * 4;
    float*  avec = (float*)(ws + off);  off += (size_t)BB * SS * 4;
    __bf16* Wth  = (__bf16*)(ws + off); off += (size_t)HH * HH * 2;
    __bf16* Wtl  = (__bf16*)(ws + off); off += (size_t)HH * HH * 2;

    int CB = 512;
    while (CB > 128 && off + 4 * (size_t)CB * SS * HH * 2 > ws_size) CB >>= 1;
    size_t xsz = (size_t)CB * SS * HH * 2;
    __bf16* Xh = (__bf16*)(ws + off); off += xsz;
    __bf16* Xl = (__bf16*)(ws + off); off += xsz;
    __bf16* Yh = (__bf16*)(ws + off); off += xsz;
    __bf16* Yl = (__bf16*)(ws + off); off += xsz;

    k_drep<<<dim3(BB, 3), 256, 0, stream>>>(X, drep);
    k_gemm_nt<<<dim3(HH / 64, BB / 64), 256, 0, stream>>>(drep, Wrel, tmat, HH, HH);
    k_splitw<<<dim3(HH / 32, HH / 32), 256, 0, stream>>>(Wsim, Wth, Wtl);

    for (int c = 0; c < BB; c += CB) {
        k_split_contrel<<<dim3(CB, 2), 512, 0, stream>>>(X + (size_t)c * SS * HH, Wc, tmat, bmat, Xh, Xl, avec, c);
        k_gemm1_mfma<<<dim3(HH / 128, CB * SS / 128), 256, 0, stream>>>(Xh, Xl, Wth, Wtl, Yh, Yl);
        k_gemm2_mfma<<<CB, 256, 0, stream>>>(Yh, Yl, Xh, Xl, avec, qbuf, c);
    }
    k_solve<<<BB, 128, 0, stream>>>(qbuf, out);
}